// Round 11
// baseline (484.556 us; speedup 1.0000x reference)
//
#include <hip/hip_runtime.h>
#include <hip/hip_bf16.h>
#include <math.h>

#define HEADS 4
#define HID 32
#define DIM 128
#define NEGS 5

typedef short s16x8 __attribute__((ext_vector_type(8)));
typedef unsigned short u16x8 __attribute__((ext_vector_type(8)));
typedef float f32x4 __attribute__((ext_vector_type(4)));

__device__ __forceinline__ unsigned short f2bf_rn(float x) {
    unsigned int u = __float_as_uint(x);
    unsigned int r = (u + 0x7FFFu + ((u >> 16) & 1u)) >> 16;
    return (unsigned short)r;
}
__device__ __forceinline__ float bf2f(unsigned short b) {
    return __uint_as_float(((unsigned int)b) << 16);
}

// ---------------------------------------------------------------------------
// Setup: zero counters/flags + weight preconvert (k-permuted) + both ee tables.
// Grid MUST be 256 blocks x 256 threads (idx 0..65535).
// Permuted slot(k): ks=k>>5, kr=k&31; kr<16 -> ks*32+(kr>>2)*8+(kr&3)
//                   else -> ks*32+((kr-16)>>2)*8+4+((kr-16)&3)
// so GEMM fragment (ks,g) = contiguous u16x8 at bt[n*128 + ks*32 + g*8],
// matching the A-side in-register pack (same k bijection; validated R10).
// ---------------------------------------------------------------------------
__global__ void k_setup(const float* __restrict__ W0, const float* __restrict__ Wres0,
                        const float* __restrict__ W1, const float* __restrict__ Wres1,
                        const float* __restrict__ eemb0, const float* __restrict__ We0,
                        const float* __restrict__ ae0,
                        const float* __restrict__ eemb1, const float* __restrict__ We1,
                        const float* __restrict__ ae1,
                        unsigned short* __restrict__ bt, float* __restrict__ eeB,
                        int* __restrict__ zbase, int zn) {
    int idx = blockIdx.x * 256 + threadIdx.x;   // 0..65535

    // zero flags/counters (grid-stride)
    for (int i = idx; i < zn; i += 65536) zbase[i] = 0;

    // weight preconvert
    {
        int layer = idx >> 15;
        int r = idx & 32767;
        int k = r >> 8;
        int n = r & 255;
        const float* src = layer ? ((n < 128) ? W1 : Wres1) : ((n < 128) ? W0 : Wres0);
        float x = src[k * 128 + (n & 127)];
        unsigned short h = f2bf_rn(x);
        unsigned short l = f2bf_rn(x - bf2f(h));
        int ks = k >> 5, kr = k & 31;
        int slot = (kr < 16) ? (ks * 32 + (kr >> 2) * 8 + (kr & 3))
                             : (ks * 32 + ((kr - 16) >> 2) * 8 + 4 + ((kr - 16) & 3));
        unsigned short* base = bt + (size_t)layer * 2 * 32768;
        base[n * 128 + slot] = h;
        base[32768 + n * 128 + slot] = l;
    }

    // ee tables for both layers (32 values)
    if (idx < 32) {
        int layer = idx >> 4, t = idx & 15;
        const float* eemb = layer ? eemb1 : eemb0;
        const float* We   = layer ? We1 : We0;
        const float* ae   = layer ? ae1 : ae0;
        int et = t >> 2, h = t & 3;
        float s = 0.f;
        for (int d = 0; d < 32; ++d) {
            float ef = 0.f;
            for (int k = 0; k < 32; ++k) ef += eemb[et * 32 + k] * We[k * DIM + h * 32 + d];
            s += ef * ae[h * 32 + d];
        }
        eeB[layer * 16 + t] = s;
    }
}

// ---------------------------------------------------------------------------
// Flags: S2 = unique(n_id); then one edge pass: histogram + flag1
// ---------------------------------------------------------------------------
__global__ void k_flag2(const int* __restrict__ n_id, int* __restrict__ flag2,
                        int* __restrict__ flag1, int M) {
    int i = blockIdx.x * 256 + threadIdx.x;
    if (i < M) { int n = n_id[i]; flag2[n] = 1; flag1[n] = 1; }
}

__global__ void k_histflag(const int* __restrict__ src, const int* __restrict__ dst,
                           const int* __restrict__ flag2,
                           int* __restrict__ counts, int* __restrict__ flag1, int E) {
    int e = blockIdx.x * 256 + threadIdx.x;
    if (e < E) {
        int d = dst[e];
        atomicAdd(&counts[d], 1);
        if (flag2[d]) flag1[src[e]] = 1;
    }
}

__global__ __launch_bounds__(1024) void k_scanA(const int* __restrict__ counts,
                                                int* __restrict__ rowtmp,
                                                int* __restrict__ bsum, int N) {
    __shared__ int s[1024];
    int i = blockIdx.x * 1024 + threadIdx.x;
    int v = (i < N) ? counts[i] : 0;
    s[threadIdx.x] = v;
    __syncthreads();
    for (int off = 1; off < 1024; off <<= 1) {
        int t = (threadIdx.x >= off) ? s[threadIdx.x - off] : 0;
        __syncthreads();
        s[threadIdx.x] += t;
        __syncthreads();
    }
    if (i < N) rowtmp[i] = s[threadIdx.x];
    if (threadIdx.x == 1023) bsum[blockIdx.x] = s[1023];
}

// Fused: block-sum scan (recomputed per block, one wave) + row_start/cursor
// + wave-aggregated compaction of list1/list2. Requires nb <= 128.
__global__ __launch_bounds__(256) void k_scanC(const int* __restrict__ rowtmp,
                                               const int* __restrict__ counts,
                                               const int* __restrict__ bsum, int nb,
                                               int* __restrict__ row_start,
                                               int* __restrict__ cursor,
                                               const int* __restrict__ flag1,
                                               const int* __restrict__ flag2,
                                               int* __restrict__ list1,
                                               int* __restrict__ list2,
                                               int* __restrict__ cnt1,
                                               int* __restrict__ cnt2, int N) {
    __shared__ int sex[128];
    int tid = threadIdx.x;
    if (tid < 64) {
        int l = tid;
        int a = (2 * l < nb) ? bsum[2 * l] : 0;
        int b = (2 * l + 1 < nb) ? bsum[2 * l + 1] : 0;
        int s = a + b;
        for (int off = 1; off < 64; off <<= 1) {
            int t = __shfl_up(s, off);
            if (l >= off) s += t;
        }
        int excl = s - (a + b);
        sex[2 * l] = excl;
        sex[2 * l + 1] = excl + a;
    }
    __syncthreads();

    int i = blockIdx.x * 256 + tid;
    int lane = tid & 63;
    if (i < N) {
        int st = rowtmp[i] - counts[i] + sex[i >> 10];
        row_start[i] = st;
        cursor[i] = st;
    }

    unsigned long long lt = (lane == 63) ? ~0ull >> 1 : (1ull << lane) - 1;
    bool a = (i < N) && flag1[i];
    unsigned long long m = __ballot(a);
    int base = 0;
    if (lane == 0 && m) base = atomicAdd(cnt1, __popcll(m));
    base = __shfl(base, 0);
    if (a) list1[base + __popcll(m & lt)] = i;

    bool b = (i < N) && flag2[i];
    m = __ballot(b);
    base = 0;
    if (lane == 0 && m) base = atomicAdd(cnt2, __popcll(m));
    base = __shfl(base, 0);
    if (b) list2[base + __popcll(m & lt)] = i;
}

__global__ void k_scatter(const int* __restrict__ dst, int* __restrict__ cursor,
                          int* __restrict__ csr_edge, int E) {
    int e = blockIdx.x * 256 + threadIdx.x;
    if (e < E) {
        int p = atomicAdd(&cursor[dst[e]], 1);
        csr_edge[p] = e;
    }
}

// ---------------------------------------------------------------------------
// No-LDS, no-barrier split-bf16 MFMA GEMM. Grid dim3(4 colchunks, nRowBlk),
// block 64 rows x 64 cols, wave = 32x32 (R7 geometry). B fragments read
// DIRECTLY from the L2-resident permuted weight arrays (one u16x8 each);
// no staging, no __syncthreads -> every wave is an independent stream
// (the k_agg regime). A: fp32 load + in-register hi/lo split.
// feat bf16 (c<2) + fused el/er; res fp32 masked by resflag (c>=2).
// C/D layout col=lane&15, row=(lane>>4)*4+reg.
// ---------------------------------------------------------------------------
template <int HASLIST>
__global__ __launch_bounds__(256, 6)
void k_gemm_ng(const float* __restrict__ A,
               const unsigned short* __restrict__ Bhi,
               const unsigned short* __restrict__ Blo,
               unsigned short* __restrict__ featb,
               float* __restrict__ res,
               const float* __restrict__ al,
               const float* __restrict__ ar,
               float* __restrict__ el,
               float* __restrict__ er,
               const int* __restrict__ rowlist,
               const int* __restrict__ rowcnt,
               const int* __restrict__ resflag,
               int N) {
    int limit = HASLIST ? *rowcnt : N;
    int c = blockIdx.x;                 // col chunk 0..3
    int m0 = blockIdx.y * 64;
    if (m0 >= limit) return;

    int tid = threadIdx.x;
    int lane = tid & 63, w = tid >> 6;
    int wm = (w & 1) * 32, wn = (w >> 1) * 32;
    int lr = lane & 15, g = lane >> 4;

    // ---- A fragments: fp32 load + in-reg hi/lo bf16 split ----
    s16x8 afh[2][4], afl[2][4];
#pragma unroll
    for (int fm = 0; fm < 2; ++fm) {
        int idx = m0 + wm + fm * 16 + lr;
        bool valid = idx < limit;
        int grow = 0;
        if (valid) grow = HASLIST ? rowlist[idx] : idx;
        const float* ap = A + (size_t)grow * DIM;
#pragma unroll
        for (int ks = 0; ks < 4; ++ks) {
            float4 p = make_float4(0.f, 0.f, 0.f, 0.f);
            float4 q = make_float4(0.f, 0.f, 0.f, 0.f);
            if (valid) {
                p = *(const float4*)(ap + ks * 32 + g * 4);
                q = *(const float4*)(ap + ks * 32 + 16 + g * 4);
            }
            float vv[8] = {p.x, p.y, p.z, p.w, q.x, q.y, q.z, q.w};
            s16x8 hv, lv;
#pragma unroll
            for (int j = 0; j < 8; ++j) {
                unsigned short hh = f2bf_rn(vv[j]);
                hv[j] = (short)hh;
                lv[j] = (short)f2bf_rn(vv[j] - bf2f(hh));
            }
            afh[fm][ks] = hv;
            afl[fm][ks] = lv;
        }
    }

    f32x4 acc[2][2];
#pragma unroll
    for (int fm = 0; fm < 2; ++fm)
#pragma unroll
        for (int fn = 0; fn < 2; ++fn) acc[fm][fn] = (f32x4){0.f, 0.f, 0.f, 0.f};

#pragma unroll
    for (int ks = 0; ks < 4; ++ks) {
        s16x8 bfh[2], bfl[2];
#pragma unroll
        for (int fn = 0; fn < 2; ++fn) {
            int brow = c * 64 + wn + fn * 16 + lr;     // 0..255
            size_t o = (size_t)brow * DIM + ks * 32 + g * 8;
            bfh[fn] = (s16x8)(*(const u16x8*)(Bhi + o));
            bfl[fn] = (s16x8)(*(const u16x8*)(Blo + o));
        }
#pragma unroll
        for (int fm = 0; fm < 2; ++fm)
#pragma unroll
            for (int fn = 0; fn < 2; ++fn) {
                acc[fm][fn] = __builtin_amdgcn_mfma_f32_16x16x32_bf16(afh[fm][ks], bfh[fn], acc[fm][fn], 0, 0, 0);
                acc[fm][fn] = __builtin_amdgcn_mfma_f32_16x16x32_bf16(afh[fm][ks], bfl[fn], acc[fm][fn], 0, 0, 0);
                acc[fm][fn] = __builtin_amdgcn_mfma_f32_16x16x32_bf16(afl[fm][ks], bfh[fn], acc[fm][fn], 0, 0, 0);
            }
    }

    // ---- C write: feat (bf16) for c<2, masked fp32 res for c>=2 ----
#pragma unroll
    for (int fm = 0; fm < 2; ++fm)
#pragma unroll
        for (int fn = 0; fn < 2; ++fn) {
            int idx0 = m0 + wm + fm * 16 + g * 4;
            int dc = ((c * 64) & 127) + wn + fn * 16 + lr;
#pragma unroll
            for (int r = 0; r < 4; ++r) {
                int idx = idx0 + r;
                if (idx < limit) {
                    int gr = HASLIST ? rowlist[idx] : idx;
                    if (c < 2) {
                        featb[(size_t)gr * DIM + dc] = f2bf_rn(acc[fm][fn][r]);
                    } else if (!resflag || resflag[gr]) {
                        res[(size_t)gr * DIM + dc] = acc[fm][fn][r];
                    }
                }
            }
        }

    // ---- fused el/er epilogue: c<2, this wave's head = 2c + wn/32 ----
    if (c < 2) {
        int h = c * 2 + (wn >> 5);
        float a0 = al[h * HID + lr], a1 = al[h * HID + 16 + lr];
        float b0 = ar[h * HID + lr], b1 = ar[h * HID + 16 + lr];
#pragma unroll
        for (int fm = 0; fm < 2; ++fm)
#pragma unroll
            for (int r = 0; r < 4; ++r) {
                float ev = acc[fm][0][r] * a0 + acc[fm][1][r] * a1;
                float rv = acc[fm][0][r] * b0 + acc[fm][1][r] * b1;
#pragma unroll
                for (int off = 1; off < 16; off <<= 1) {
                    ev += __shfl_xor(ev, off);
                    rv += __shfl_xor(rv, off);
                }
                if (lr == 0) {
                    int idx = m0 + wm + fm * 16 + g * 4 + r;
                    if (idx < limit) {
                        int node = HASLIST ? rowlist[idx] : idx;
                        el[node * 4 + h] = ev;
                        er[node * 4 + h] = rv;
                    }
                }
            }
    }
}

// ---------------------------------------------------------------------------
// Aggregation over a dst-node list: one wave per listed dst node. feat bf16.
// ---------------------------------------------------------------------------
template <int RELU>
__global__ __launch_bounds__(256) void k_agg(const unsigned short* __restrict__ featb,
                                             const float* __restrict__ el,
                                             const float* __restrict__ er,
                                             const float* __restrict__ eeB,
                                             const int* __restrict__ srcArr,
                                             const int* __restrict__ etArr,
                                             const int* __restrict__ csr_edge,
                                             const int* __restrict__ row_start,
                                             const int* __restrict__ counts,
                                             const int* __restrict__ dlist,
                                             const int* __restrict__ dcnt,
                                             float* __restrict__ out) {
    int wv = threadIdx.x >> 6;
    int lane = threadIdx.x & 63;
    int idx = blockIdx.x * 4 + wv;
    if (idx >= *dcnt) return;
    int node = dlist[idx];

    int beg = row_start[node];
    int deg = counts[node];
    int eh = lane & 3;
    float er_v = er[node * 4 + eh];

    float m = -INFINITY;
    for (int base = 0; base < deg; base += 16) {
        int ei = base + (lane >> 2);
        float lg = -INFINITY;
        if (ei < deg) {
            int e = csr_edge[beg + ei];
            float x = el[srcArr[e] * 4 + eh] + er_v + eeB[etArr[e] * 4 + eh];
            lg = (x > 0.f) ? x : 0.2f * x;
        }
        m = fmaxf(m, lg);
    }
    for (int off = 4; off < 64; off <<= 1) m = fmaxf(m, __shfl_xor(m, off));

    float denom = 0.f, acc0 = 0.f, acc1 = 0.f;
    int h1 = lane >> 5;
    for (int base = 0; base < deg; base += 16) {
        int ei = base + (lane >> 2);
        float wgt = 0.f;
        int s = 0;
        if (ei < deg) {
            int e = csr_edge[beg + ei];
            s = srcArr[e];
            float x = el[s * 4 + eh] + er_v + eeB[etArr[e] * 4 + eh];
            x = (x > 0.f) ? x : 0.2f * x;
            wgt = expf(x - m);
            denom += wgt;
        }
        int cnt = min(16, deg - base);
        for (int j = 0; j < cnt; ++j) {
            int sj = __shfl(s, j * 4);
            float w1 = __shfl(wgt, j * 4 + h1);
            float w2 = __shfl(wgt, j * 4 + 2 + h1);
            acc0 += w1 * bf2f(featb[(size_t)sj * DIM + lane]);
            acc1 += w2 * bf2f(featb[(size_t)sj * DIM + 64 + lane]);
        }
    }
    for (int off = 4; off < 64; off <<= 1) denom += __shfl_xor(denom, off);
    float d1 = __shfl(denom, h1);
    float d2 = __shfl(denom, 2 + h1);

    float r0 = out[(size_t)node * DIM + lane] + acc0 / (d1 + 1e-16f);
    float r1 = out[(size_t)node * DIM + 64 + lane] + acc1 / (d2 + 1e-16f);
    if (RELU) { r0 = fmaxf(r0, 0.f); r1 = fmaxf(r1, 0.f); }
    out[(size_t)node * DIM + lane] = r0;
    out[(size_t)node * DIM + 64 + lane] = r1;
}

// ---------------------------------------------------------------------------
// Head MLP
// ---------------------------------------------------------------------------
__global__ __launch_bounds__(256) void k_head(const float* __restrict__ x1,
                                              const int* __restrict__ n_id,
                                              const float* __restrict__ pW1,
                                              const float* __restrict__ pb1,
                                              const float* __restrict__ pW2,
                                              const float* __restrict__ pb2,
                                              float* __restrict__ dout, int B) {
    int o = blockIdx.x * 4 + (threadIdx.x >> 6);
    int lane = threadIdx.x & 63;
    int total = B + B * NEGS;
    if (o >= total) return;
    int a, c;
    if (o < B) { a = n_id[o]; c = n_id[B + o]; }
    else { int j = o - B; a = n_id[j / NEGS]; c = n_id[2 * B + j]; }

    int j = lane & 31;
    int half = lane >> 5;
    int row = half ? c : a;
    const float* z = x1 + (size_t)row * DIM;
    const float* w = pW1 + (half ? 128 * 32 : 0);
    float t = 0.f;
#pragma unroll 8
    for (int k = 0; k < 128; ++k) t += z[k] * w[k * 32 + j];
    t += __shfl_xor(t, 32);
    t += pb1[j];
    t = (t > 0.f) ? t : 0.2f * t;
    float r = t * pW2[j];
    for (int off = 1; off < 32; off <<= 1) r += __shfl_xor(r, off);
    if (lane == 0) dout[o] = r + pb2[0];
}

// ---------------------------------------------------------------------------
extern "C" void kernel_launch(void* const* d_in, const int* in_sizes, int n_in,
                              void* d_out, int out_size, void* d_ws, size_t ws_size,
                              hipStream_t stream) {
    const int* edge_index = (const int*)d_in[0];
    const int* etype      = (const int*)d_in[1];
    const int* n_id       = (const int*)d_in[2];
    const float* id_emb   = (const float*)d_in[4];
    const float* W0    = (const float*)d_in[5];
    const float* Wres0 = (const float*)d_in[6];
    const float* al0   = (const float*)d_in[7];
    const float* ar0   = (const float*)d_in[8];
    const float* ae0   = (const float*)d_in[9];
    const float* eemb0 = (const float*)d_in[10];
    const float* We0   = (const float*)d_in[11];
    const float* W1    = (const float*)d_in[12];
    const float* Wres1 = (const float*)d_in[13];
    const float* al1   = (const float*)d_in[14];
    const float* ar1   = (const float*)d_in[15];
    const float* ae1   = (const float*)d_in[16];
    const float* eemb1 = (const float*)d_in[17];
    const float* We1   = (const float*)d_in[18];
    const float* pW1   = (const float*)d_in[19];
    const float* pb1   = (const float*)d_in[20];
    const float* pW2   = (const float*)d_in[21];
    const float* pb2   = (const float*)d_in[22];

    int E = in_sizes[1];
    int N = in_sizes[4] / DIM;
    int M = in_sizes[2];
    int B = M / (2 + NEGS);
    const int* srcArr = edge_index;
    const int* dstArr = edge_index + E;

    size_t N128 = (size_t)N * DIM;
    unsigned short* featb = (unsigned short*)d_ws;     // N128 u16
    float* x0   = (float*)(featb + N128);              // N128 f32
    float* x1   = x0 + N128;                           // N128 f32
    float* el   = x1 + N128;
    float* er   = el + (size_t)N * 4;
    float* eeB  = er + (size_t)N * 4;                  // 32 (both layers)
    int* counts    = (int*)(eeB + 32);
    int* flag1     = counts + N;
    int* flag2     = flag1 + N;
    int* cnt1      = flag2 + N;
    int* cnt2      = cnt1 + 1;
    int* rowtmp    = cnt2 + 1;
    int* row_start = rowtmp + N;
    int* cursor    = row_start + N;
    int* csr_edge  = cursor + N;
    int* list1     = csr_edge + E;
    int* list2     = list1 + N;
    int* bsum      = list2 + M;
    unsigned short* bt = (unsigned short*)(bsum + 256);

    // ---- setup: zero(3N+2) + wcvt(permuted) + both ee tables ----
    k_setup<<<256, 256, 0, stream>>>(W0, Wres0, W1, Wres1,
                                     eemb0, We0, ae0, eemb1, We1, ae1,
                                     bt, eeB, counts, 3 * N + 2);

    // ---- flags, CSR ----
    k_flag2<<<(M + 255) / 256, 256, 0, stream>>>(n_id, flag2, flag1, M);
    k_histflag<<<(E + 255) / 256, 256, 0, stream>>>(srcArr, dstArr, flag2, counts, flag1, E);
    int nb = (N + 1023) / 1024;
    k_scanA<<<nb, 1024, 0, stream>>>(counts, rowtmp, bsum, N);
    k_scanC<<<(N + 255) / 256, 256, 0, stream>>>(rowtmp, counts, bsum, nb, row_start, cursor,
                                                 flag1, flag2, list1, list2, cnt1, cnt2, N);
    k_scatter<<<(E + 255) / 256, 256, 0, stream>>>(dstArr, cursor, csr_edge, E);

    dim3 ggrid(4, (N + 63) / 64);
    int aggGridFull = (N + 3) / 4;
    int aggGridS2 = (M + 3) / 4;

    // ---- layer 0 ----
    k_gemm_ng<0><<<ggrid, 256, 0, stream>>>(id_emb, bt, bt + 32768,
                                            featb, x0, al0, ar0, el, er,
                                            nullptr, nullptr, flag1, N);
    k_agg<1><<<aggGridFull, 256, 0, stream>>>(featb, el, er, eeB, srcArr, etype, csr_edge,
                                              row_start, counts, list1, cnt1, x0);

    // ---- layer 1 ----
    k_gemm_ng<1><<<ggrid, 256, 0, stream>>>(x0, bt + 65536, bt + 98304,
                                            featb, x1, al1, ar1, el, er,
                                            list1, cnt1, flag2, N);
    k_agg<0><<<aggGridS2, 256, 0, stream>>>(featb, el, er, eeB + 16, srcArr, etype, csr_edge,
                                            row_start, counts, list2, cnt2, x1);

    // ---- head ----
    int total = B * (1 + NEGS);
    k_head<<<(total + 3) / 4, 256, 0, stream>>>(x1, n_id, pW1, pb1, pW2, pb2,
                                                (float*)d_out, B);
}

// Round 12
// 454.411 us; speedup vs baseline: 1.0663x; 1.0663x over previous
//
#include <hip/hip_runtime.h>
#include <hip/hip_bf16.h>
#include <math.h>

#define HEADS 4
#define HID 32
#define DIM 128
#define NEGS 5

typedef short s16x8 __attribute__((ext_vector_type(8)));
typedef unsigned short u16x8 __attribute__((ext_vector_type(8)));
typedef float f32x4 __attribute__((ext_vector_type(4)));

__device__ __forceinline__ unsigned short f2bf_rn(float x) {
    unsigned int u = __float_as_uint(x);
    unsigned int r = (u + 0x7FFFu + ((u >> 16) & 1u)) >> 16;
    return (unsigned short)r;
}
__device__ __forceinline__ float bf2f(unsigned short b) {
    return __uint_as_float(((unsigned int)b) << 16);
}

// ---------------------------------------------------------------------------
// Setup: zero counters/flags + weight preconvert (k-permuted) + both ee tables.
// Grid MUST be 256 x 256 (idx 0..65535).
// Permuted slot(k): fragment (ks,g) = contiguous u16x8 at bt[n*128+ks*32+g*8]
// in A-pack order [p0..p3,q0..q3] (k = ks*32+g*4+j and +16). Validated R10/R11.
// ---------------------------------------------------------------------------
__global__ void k_setup(const float* __restrict__ W0, const float* __restrict__ Wres0,
                        const float* __restrict__ W1, const float* __restrict__ Wres1,
                        const float* __restrict__ eemb0, const float* __restrict__ We0,
                        const float* __restrict__ ae0,
                        const float* __restrict__ eemb1, const float* __restrict__ We1,
                        const float* __restrict__ ae1,
                        unsigned short* __restrict__ bt, float* __restrict__ eeB,
                        int* __restrict__ zbase, int zn) {
    int idx = blockIdx.x * 256 + threadIdx.x;

    for (int i = idx; i < zn; i += 65536) zbase[i] = 0;

    {
        int layer = idx >> 15;
        int r = idx & 32767;
        int k = r >> 8;
        int n = r & 255;
        const float* src = layer ? ((n < 128) ? W1 : Wres1) : ((n < 128) ? W0 : Wres0);
        float x = src[k * 128 + (n & 127)];
        unsigned short h = f2bf_rn(x);
        unsigned short l = f2bf_rn(x - bf2f(h));
        int ks = k >> 5, kr = k & 31;
        int slot = (kr < 16) ? (ks * 32 + (kr >> 2) * 8 + (kr & 3))
                             : (ks * 32 + ((kr - 16) >> 2) * 8 + 4 + ((kr - 16) & 3));
        unsigned short* base = bt + (size_t)layer * 2 * 32768;
        base[n * 128 + slot] = h;
        base[32768 + n * 128 + slot] = l;
    }

    if (idx < 32) {
        int layer = idx >> 4, t = idx & 15;
        const float* eemb = layer ? eemb1 : eemb0;
        const float* We   = layer ? We1 : We0;
        const float* ae   = layer ? ae1 : ae0;
        int et = t >> 2, h = t & 3;
        float s = 0.f;
        for (int d = 0; d < 32; ++d) {
            float ef = 0.f;
            for (int k = 0; k < 32; ++k) ef += eemb[et * 32 + k] * We[k * DIM + h * 32 + d];
            s += ef * ae[h * 32 + d];
        }
        eeB[layer * 16 + t] = s;
    }
}

// ---------------------------------------------------------------------------
// Flags + CSR build
// ---------------------------------------------------------------------------
__global__ void k_flag2(const int* __restrict__ n_id, int* __restrict__ flag2,
                        int* __restrict__ flag1, int M) {
    int i = blockIdx.x * 256 + threadIdx.x;
    if (i < M) { int n = n_id[i]; flag2[n] = 1; flag1[n] = 1; }
}

__global__ void k_histflag(const int* __restrict__ src, const int* __restrict__ dst,
                           const int* __restrict__ flag2,
                           int* __restrict__ counts, int* __restrict__ flag1, int E) {
    int e = blockIdx.x * 256 + threadIdx.x;
    if (e < E) {
        int d = dst[e];
        atomicAdd(&counts[d], 1);
        if (flag2[d]) flag1[src[e]] = 1;
    }
}

__global__ __launch_bounds__(1024) void k_scanA(const int* __restrict__ counts,
                                                int* __restrict__ rowtmp,
                                                int* __restrict__ bsum, int N) {
    __shared__ int s[1024];
    int i = blockIdx.x * 1024 + threadIdx.x;
    int v = (i < N) ? counts[i] : 0;
    s[threadIdx.x] = v;
    __syncthreads();
    for (int off = 1; off < 1024; off <<= 1) {
        int t = (threadIdx.x >= off) ? s[threadIdx.x - off] : 0;
        __syncthreads();
        s[threadIdx.x] += t;
        __syncthreads();
    }
    if (i < N) rowtmp[i] = s[threadIdx.x];
    if (threadIdx.x == 1023) bsum[blockIdx.x] = s[1023];
}

// Fused: block-sum scan (recomputed per block) + row_start/cursor + compaction.
__global__ __launch_bounds__(256) void k_scanC(const int* __restrict__ rowtmp,
                                               const int* __restrict__ counts,
                                               const int* __restrict__ bsum, int nb,
                                               int* __restrict__ row_start,
                                               int* __restrict__ cursor,
                                               const int* __restrict__ flag1,
                                               const int* __restrict__ flag2,
                                               int* __restrict__ list1,
                                               int* __restrict__ list2,
                                               int* __restrict__ cnt1,
                                               int* __restrict__ cnt2, int N) {
    __shared__ int sex[128];
    int tid = threadIdx.x;
    if (tid < 64) {
        int l = tid;
        int a = (2 * l < nb) ? bsum[2 * l] : 0;
        int b = (2 * l + 1 < nb) ? bsum[2 * l + 1] : 0;
        int s = a + b;
        for (int off = 1; off < 64; off <<= 1) {
            int t = __shfl_up(s, off);
            if (l >= off) s += t;
        }
        int excl = s - (a + b);
        sex[2 * l] = excl;
        sex[2 * l + 1] = excl + a;
    }
    __syncthreads();

    int i = blockIdx.x * 256 + tid;
    int lane = tid & 63;
    if (i < N) {
        int st = rowtmp[i] - counts[i] + sex[i >> 10];
        row_start[i] = st;
        cursor[i] = st;
    }

    unsigned long long lt = (lane == 63) ? ~0ull >> 1 : (1ull << lane) - 1;
    bool a = (i < N) && flag1[i];
    unsigned long long m = __ballot(a);
    int base = 0;
    if (lane == 0 && m) base = atomicAdd(cnt1, __popcll(m));
    base = __shfl(base, 0);
    if (a) list1[base + __popcll(m & lt)] = i;

    bool b = (i < N) && flag2[i];
    m = __ballot(b);
    base = 0;
    if (lane == 0 && m) base = atomicAdd(cnt2, __popcll(m));
    base = __shfl(base, 0);
    if (b) list2[base + __popcll(m & lt)] = i;
}

__global__ void k_scatter(const int* __restrict__ dst, int* __restrict__ cursor,
                          int* __restrict__ csr_edge, int E) {
    int e = blockIdx.x * 256 + threadIdx.x;
    if (e < E) {
        int p = atomicAdd(&cursor[dst[e]], 1);
        csr_edge[p] = e;
    }
}

// ---------------------------------------------------------------------------
// R7-structure split-bf16 MFMA GEMM with permuted-B single-b128 LDS reads.
// Grid dim3(4 colchunks, nRowBlk), block 64x64, wave = 32x32.
// B staged (pre-permuted) into LDS w/ XOR swizzle; fragment = ONE ds_read_b128.
// A: fp32 float4-pair load + in-register hi/lo split (bit-identical chain).
// feat bf16 (c<2) + fused el/er; res fp32 masked by resflag (c>=2).
// C/D layout col=lane&15, row=(lane>>4)*4+reg.
// ---------------------------------------------------------------------------
template <int HASLIST>
__global__ __launch_bounds__(256, 5)
void k_gemm_fused(const float* __restrict__ A,
                  const unsigned short* __restrict__ Bhi,
                  const unsigned short* __restrict__ Blo,
                  unsigned short* __restrict__ featb,
                  float* __restrict__ res,
                  const float* __restrict__ al,
                  const float* __restrict__ ar,
                  float* __restrict__ el,
                  float* __restrict__ er,
                  const int* __restrict__ rowlist,
                  const int* __restrict__ rowcnt,
                  const int* __restrict__ resflag,
                  int N) {
    int limit = HASLIST ? *rowcnt : N;
    int c = blockIdx.x;
    int m0 = blockIdx.y * 64;
    if (m0 >= limit) return;

    __shared__ unsigned short Bh[8192];
    __shared__ unsigned short Bl[8192];
    int tid = threadIdx.x;
    int lane = tid & 63, w = tid >> 6;
    int wm = (w & 1) * 32, wn = (w >> 1) * 32;
    int lr = lane & 15, g = lane >> 4;

    // stage permuted B chunk, swizzled: byte ^= (row&7)<<4
#pragma unroll
    for (int i = 0; i < 4; ++i) {
        int f = tid + i * 256;
        int row = f >> 4, g16 = f & 15;
        int off = (row * 256 + ((g16 * 16) ^ ((row & 7) << 4))) >> 1;
        *(u16x8*)&Bh[off] = *(const u16x8*)(Bhi + (size_t)(c * 64 + row) * DIM + g16 * 8);
        *(u16x8*)&Bl[off] = *(const u16x8*)(Blo + (size_t)(c * 64 + row) * DIM + g16 * 8);
    }

    // A fragments: fp32 load + in-reg hi/lo bf16 split
    s16x8 afh[2][4], afl[2][4];
#pragma unroll
    for (int fm = 0; fm < 2; ++fm) {
        int idx = m0 + wm + fm * 16 + lr;
        bool valid = idx < limit;
        int grow = 0;
        if (valid) grow = HASLIST ? rowlist[idx] : idx;
        const float* ap = A + (size_t)grow * DIM;
#pragma unroll
        for (int ks = 0; ks < 4; ++ks) {
            float4 p = make_float4(0.f, 0.f, 0.f, 0.f);
            float4 q = make_float4(0.f, 0.f, 0.f, 0.f);
            if (valid) {
                p = *(const float4*)(ap + ks * 32 + g * 4);
                q = *(const float4*)(ap + ks * 32 + 16 + g * 4);
            }
            float vv[8] = {p.x, p.y, p.z, p.w, q.x, q.y, q.z, q.w};
            s16x8 hv, lv;
#pragma unroll
            for (int j = 0; j < 8; ++j) {
                unsigned short hh = f2bf_rn(vv[j]);
                hv[j] = (short)hh;
                lv[j] = (short)f2bf_rn(vv[j] - bf2f(hh));
            }
            afh[fm][ks] = hv;
            afl[fm][ks] = lv;
        }
    }
    __syncthreads();

    f32x4 acc[2][2];
#pragma unroll
    for (int fm = 0; fm < 2; ++fm)
#pragma unroll
        for (int fn = 0; fn < 2; ++fn) acc[fm][fn] = (f32x4){0.f, 0.f, 0.f, 0.f};

#pragma unroll
    for (int ks = 0; ks < 4; ++ks) {
        s16x8 bfh[2], bfl[2];
#pragma unroll
        for (int fn = 0; fn < 2; ++fn) {
            int row = wn + fn * 16 + lr;
            int off = (row * 256 + ((ks * 64 + g * 16) ^ ((row & 7) << 4))) >> 1;
            bfh[fn] = *(const s16x8*)&Bh[off];     // single ds_read_b128
            bfl[fn] = *(const s16x8*)&Bl[off];
        }
#pragma unroll
        for (int fm = 0; fm < 2; ++fm)
#pragma unroll
            for (int fn = 0; fn < 2; ++fn) {
                acc[fm][fn] = __builtin_amdgcn_mfma_f32_16x16x32_bf16(afh[fm][ks], bfh[fn], acc[fm][fn], 0, 0, 0);
                acc[fm][fn] = __builtin_amdgcn_mfma_f32_16x16x32_bf16(afh[fm][ks], bfl[fn], acc[fm][fn], 0, 0, 0);
                acc[fm][fn] = __builtin_amdgcn_mfma_f32_16x16x32_bf16(afl[fm][ks], bfh[fn], acc[fm][fn], 0, 0, 0);
            }
    }

    // C write: feat (bf16) for c<2, masked fp32 res for c>=2
#pragma unroll
    for (int fm = 0; fm < 2; ++fm)
#pragma unroll
        for (int fn = 0; fn < 2; ++fn) {
            int idx0 = m0 + wm + fm * 16 + g * 4;
            int dc = ((c * 64) & 127) + wn + fn * 16 + lr;
#pragma unroll
            for (int r = 0; r < 4; ++r) {
                int idx = idx0 + r;
                if (idx < limit) {
                    int gr = HASLIST ? rowlist[idx] : idx;
                    if (c < 2) {
                        featb[(size_t)gr * DIM + dc] = f2bf_rn(acc[fm][fn][r]);
                    } else if (!resflag || resflag[gr]) {
                        res[(size_t)gr * DIM + dc] = acc[fm][fn][r];
                    }
                }
            }
        }

    // fused el/er epilogue: c<2, this wave's head = 2c + wn/32
    if (c < 2) {
        int h = c * 2 + (wn >> 5);
        float a0 = al[h * HID + lr], a1 = al[h * HID + 16 + lr];
        float b0 = ar[h * HID + lr], b1 = ar[h * HID + 16 + lr];
#pragma unroll
        for (int fm = 0; fm < 2; ++fm)
#pragma unroll
            for (int r = 0; r < 4; ++r) {
                float ev = acc[fm][0][r] * a0 + acc[fm][1][r] * a1;
                float rv = acc[fm][0][r] * b0 + acc[fm][1][r] * b1;
#pragma unroll
                for (int off = 1; off < 16; off <<= 1) {
                    ev += __shfl_xor(ev, off);
                    rv += __shfl_xor(rv, off);
                }
                if (lr == 0) {
                    int idx = m0 + wm + fm * 16 + g * 4 + r;
                    if (idx < limit) {
                        int node = HASLIST ? rowlist[idx] : idx;
                        el[node * 4 + h] = ev;
                        er[node * 4 + h] = rv;
                    }
                }
            }
    }
}

// ---------------------------------------------------------------------------
// Aggregation over a dst-node list: one wave per listed dst node. feat bf16.
// ---------------------------------------------------------------------------
template <int RELU>
__global__ __launch_bounds__(256) void k_agg(const unsigned short* __restrict__ featb,
                                             const float* __restrict__ el,
                                             const float* __restrict__ er,
                                             const float* __restrict__ eeB,
                                             const int* __restrict__ srcArr,
                                             const int* __restrict__ etArr,
                                             const int* __restrict__ csr_edge,
                                             const int* __restrict__ row_start,
                                             const int* __restrict__ counts,
                                             const int* __restrict__ dlist,
                                             const int* __restrict__ dcnt,
                                             float* __restrict__ out) {
    int wv = threadIdx.x >> 6;
    int lane = threadIdx.x & 63;
    int idx = blockIdx.x * 4 + wv;
    if (idx >= *dcnt) return;
    int node = dlist[idx];

    int beg = row_start[node];
    int deg = counts[node];
    int eh = lane & 3;
    float er_v = er[node * 4 + eh];

    float m = -INFINITY;
    for (int base = 0; base < deg; base += 16) {
        int ei = base + (lane >> 2);
        float lg = -INFINITY;
        if (ei < deg) {
            int e = csr_edge[beg + ei];
            float x = el[srcArr[e] * 4 + eh] + er_v + eeB[etArr[e] * 4 + eh];
            lg = (x > 0.f) ? x : 0.2f * x;
        }
        m = fmaxf(m, lg);
    }
    for (int off = 4; off < 64; off <<= 1) m = fmaxf(m, __shfl_xor(m, off));

    float denom = 0.f, acc0 = 0.f, acc1 = 0.f;
    int h1 = lane >> 5;
    for (int base = 0; base < deg; base += 16) {
        int ei = base + (lane >> 2);
        float wgt = 0.f;
        int s = 0;
        if (ei < deg) {
            int e = csr_edge[beg + ei];
            s = srcArr[e];
            float x = el[s * 4 + eh] + er_v + eeB[etArr[e] * 4 + eh];
            x = (x > 0.f) ? x : 0.2f * x;
            wgt = expf(x - m);
            denom += wgt;
        }
        int cnt = min(16, deg - base);
        for (int j = 0; j < cnt; ++j) {
            int sj = __shfl(s, j * 4);
            float w1 = __shfl(wgt, j * 4 + h1);
            float w2 = __shfl(wgt, j * 4 + 2 + h1);
            acc0 += w1 * bf2f(featb[(size_t)sj * DIM + lane]);
            acc1 += w2 * bf2f(featb[(size_t)sj * DIM + 64 + lane]);
        }
    }
    for (int off = 4; off < 64; off <<= 1) denom += __shfl_xor(denom, off);
    float d1 = __shfl(denom, h1);
    float d2 = __shfl(denom, 2 + h1);

    float r0 = out[(size_t)node * DIM + lane] + acc0 / (d1 + 1e-16f);
    float r1 = out[(size_t)node * DIM + 64 + lane] + acc1 / (d2 + 1e-16f);
    if (RELU) { r0 = fmaxf(r0, 0.f); r1 = fmaxf(r1, 0.f); }
    out[(size_t)node * DIM + lane] = r0;
    out[(size_t)node * DIM + 64 + lane] = r1;
}

// ---------------------------------------------------------------------------
// Head MLP
// ---------------------------------------------------------------------------
__global__ __launch_bounds__(256) void k_head(const float* __restrict__ x1,
                                              const int* __restrict__ n_id,
                                              const float* __restrict__ pW1,
                                              const float* __restrict__ pb1,
                                              const float* __restrict__ pW2,
                                              const float* __restrict__ pb2,
                                              float* __restrict__ dout, int B) {
    int o = blockIdx.x * 4 + (threadIdx.x >> 6);
    int lane = threadIdx.x & 63;
    int total = B + B * NEGS;
    if (o >= total) return;
    int a, c;
    if (o < B) { a = n_id[o]; c = n_id[B + o]; }
    else { int j = o - B; a = n_id[j / NEGS]; c = n_id[2 * B + j]; }

    int j = lane & 31;
    int half = lane >> 5;
    int row = half ? c : a;
    const float* z = x1 + (size_t)row * DIM;
    const float* w = pW1 + (half ? 128 * 32 : 0);
    float t = 0.f;
#pragma unroll 8
    for (int k = 0; k < 128; ++k) t += z[k] * w[k * 32 + j];
    t += __shfl_xor(t, 32);
    t += pb1[j];
    t = (t > 0.f) ? t : 0.2f * t;
    float r = t * pW2[j];
    for (int off = 1; off < 32; off <<= 1) r += __shfl_xor(r, off);
    if (lane == 0) dout[o] = r + pb2[0];
}

// ---------------------------------------------------------------------------
extern "C" void kernel_launch(void* const* d_in, const int* in_sizes, int n_in,
                              void* d_out, int out_size, void* d_ws, size_t ws_size,
                              hipStream_t stream) {
    const int* edge_index = (const int*)d_in[0];
    const int* etype      = (const int*)d_in[1];
    const int* n_id       = (const int*)d_in[2];
    const float* id_emb   = (const float*)d_in[4];
    const float* W0    = (const float*)d_in[5];
    const float* Wres0 = (const float*)d_in[6];
    const float* al0   = (const float*)d_in[7];
    const float* ar0   = (const float*)d_in[8];
    const float* ae0   = (const float*)d_in[9];
    const float* eemb0 = (const float*)d_in[10];
    const float* We0   = (const float*)d_in[11];
    const float* W1    = (const float*)d_in[12];
    const float* Wres1 = (const float*)d_in[13];
    const float* al1   = (const float*)d_in[14];
    const float* ar1   = (const float*)d_in[15];
    const float* ae1   = (const float*)d_in[16];
    const float* eemb1 = (const float*)d_in[17];
    const float* We1   = (const float*)d_in[18];
    const float* pW1   = (const float*)d_in[19];
    const float* pb1   = (const float*)d_in[20];
    const float* pW2   = (const float*)d_in[21];
    const float* pb2   = (const float*)d_in[22];

    int E = in_sizes[1];
    int N = in_sizes[4] / DIM;
    int M = in_sizes[2];
    int B = M / (2 + NEGS);
    const int* srcArr = edge_index;
    const int* dstArr = edge_index + E;

    size_t N128 = (size_t)N * DIM;
    unsigned short* featb = (unsigned short*)d_ws;     // N128 u16
    float* x0   = (float*)(featb + N128);              // N128 f32
    float* x1   = x0 + N128;                           // N128 f32
    float* el   = x1 + N128;
    float* er   = el + (size_t)N * 4;
    float* eeB  = er + (size_t)N * 4;                  // 32 floats (both layers)
    int* counts    = (int*)(eeB + 32);
    int* flag1     = counts + N;
    int* flag2     = flag1 + N;
    int* cnt1      = flag2 + N;
    int* cnt2      = cnt1 + 1;
    int* rowtmp    = cnt2 + 1;
    int* row_start = rowtmp + N;
    int* cursor    = row_start + N;
    int* csr_edge  = cursor + N;
    int* list1     = csr_edge + E;
    int* list2     = list1 + N;
    int* bsum      = list2 + M;
    unsigned short* bt = (unsigned short*)(bsum + 256);

    // ---- setup: zero(3N+2) + wcvt(permuted) + both ee tables ----
    k_setup<<<256, 256, 0, stream>>>(W0, Wres0, W1, Wres1,
                                     eemb0, We0, ae0, eemb1, We1, ae1,
                                     bt, eeB, counts, 3 * N + 2);

    // ---- flags, CSR ----
    k_flag2<<<(M + 255) / 256, 256, 0, stream>>>(n_id, flag2, flag1, M);
    k_histflag<<<(E + 255) / 256, 256, 0, stream>>>(srcArr, dstArr, flag2, counts, flag1, E);
    int nb = (N + 1023) / 1024;
    k_scanA<<<nb, 1024, 0, stream>>>(counts, rowtmp, bsum, N);
    k_scanC<<<(N + 255) / 256, 256, 0, stream>>>(rowtmp, counts, bsum, nb, row_start, cursor,
                                                 flag1, flag2, list1, list2, cnt1, cnt2, N);
    k_scatter<<<(E + 255) / 256, 256, 0, stream>>>(dstArr, cursor, csr_edge, E);

    dim3 ggrid(4, (N + 63) / 64);
    int aggGridFull = (N + 3) / 4;
    int aggGridS2 = (M + 3) / 4;

    // ---- layer 0 ----
    k_gemm_fused<0><<<ggrid, 256, 0, stream>>>(id_emb, bt, bt + 32768,
                                               featb, x0, al0, ar0, el, er,
                                               nullptr, nullptr, flag1, N);
    k_agg<1><<<aggGridFull, 256, 0, stream>>>(featb, el, er, eeB, srcArr, etype, csr_edge,
                                              row_start, counts, list1, cnt1, x0);

    // ---- layer 1 ----
    k_gemm_fused<1><<<ggrid, 256, 0, stream>>>(x0, bt + 65536, bt + 98304,
                                               featb, x1, al1, ar1, el, er,
                                               list1, cnt1, flag2, N);
    k_agg<0><<<aggGridS2, 256, 0, stream>>>(featb, el, er, eeB + 16, srcArr, etype, csr_edge,
                                            row_start, counts, list2, cnt2, x1);

    // ---- head ----
    int total = B * (1 + NEGS);
    k_head<<<(total + 3) / 4, 256, 0, stream>>>(x1, n_id, pW1, pb1, pW2, pb2,
                                                (float*)d_out, B);
}

// Round 13
// 369.597 us; speedup vs baseline: 1.3110x; 1.2295x over previous
//
#include <hip/hip_runtime.h>
#include <hip/hip_bf16.h>
#include <math.h>

#define HEADS 4
#define HID 32
#define DIM 128
#define NEGS 5

typedef short s16x8 __attribute__((ext_vector_type(8)));
typedef short s16x4 __attribute__((ext_vector_type(4)));
typedef unsigned short u16x8 __attribute__((ext_vector_type(8)));
typedef float f32x4 __attribute__((ext_vector_type(4)));

__device__ __forceinline__ unsigned short f2bf_rn(float x) {
    unsigned int u = __float_as_uint(x);
    unsigned int r = (u + 0x7FFFu + ((u >> 16) & 1u)) >> 16;
    return (unsigned short)r;
}
__device__ __forceinline__ float bf2f(unsigned short b) {
    return __uint_as_float(((unsigned int)b) << 16);
}

// ---------------------------------------------------------------------------
// Setup: zero counters/flags + weight preconvert (UNPERMUTED, R7 layout:
// bt[layer][hi/lo][n][k]) + both ee tables. Grid MUST be 256 x 256.
// ---------------------------------------------------------------------------
__global__ void k_setup(const float* __restrict__ W0, const float* __restrict__ Wres0,
                        const float* __restrict__ W1, const float* __restrict__ Wres1,
                        const float* __restrict__ eemb0, const float* __restrict__ We0,
                        const float* __restrict__ ae0,
                        const float* __restrict__ eemb1, const float* __restrict__ We1,
                        const float* __restrict__ ae1,
                        unsigned short* __restrict__ bt, float* __restrict__ eeB,
                        int* __restrict__ zbase, int zn) {
    int idx = blockIdx.x * 256 + threadIdx.x;

    for (int i = idx; i < zn; i += 65536) zbase[i] = 0;

    {
        int layer = idx >> 15;
        int r = idx & 32767;
        int k = r >> 8;
        int n = r & 255;
        const float* src = layer ? ((n < 128) ? W1 : Wres1) : ((n < 128) ? W0 : Wres0);
        float x = src[k * 128 + (n & 127)];
        unsigned short h = f2bf_rn(x);
        unsigned short l = f2bf_rn(x - bf2f(h));
        unsigned short* base = bt + (size_t)layer * 2 * 32768;
        base[n * 128 + k] = h;
        base[32768 + n * 128 + k] = l;
    }

    if (idx < 32) {
        int layer = idx >> 4, t = idx & 15;
        const float* eemb = layer ? eemb1 : eemb0;
        const float* We   = layer ? We1 : We0;
        const float* ae   = layer ? ae1 : ae0;
        int et = t >> 2, h = t & 3;
        float s = 0.f;
        for (int d = 0; d < 32; ++d) {
            float ef = 0.f;
            for (int k = 0; k < 32; ++k) ef += eemb[et * 32 + k] * We[k * DIM + h * 32 + d];
            s += ef * ae[h * 32 + d];
        }
        eeB[layer * 16 + t] = s;
    }
}

// ---------------------------------------------------------------------------
// Flags + CSR build
// ---------------------------------------------------------------------------
__global__ void k_flag2(const int* __restrict__ n_id, int* __restrict__ flag2,
                        int* __restrict__ flag1, int M) {
    int i = blockIdx.x * 256 + threadIdx.x;
    if (i < M) { int n = n_id[i]; flag2[n] = 1; flag1[n] = 1; }
}

__global__ void k_histflag(const int* __restrict__ src, const int* __restrict__ dst,
                           const int* __restrict__ flag2,
                           int* __restrict__ counts, int* __restrict__ flag1, int E) {
    int e = blockIdx.x * 256 + threadIdx.x;
    if (e < E) {
        int d = dst[e];
        atomicAdd(&counts[d], 1);
        if (flag2[d]) flag1[src[e]] = 1;
    }
}

__global__ __launch_bounds__(1024) void k_scanA(const int* __restrict__ counts,
                                                int* __restrict__ rowtmp,
                                                int* __restrict__ bsum, int N) {
    __shared__ int s[1024];
    int i = blockIdx.x * 1024 + threadIdx.x;
    int v = (i < N) ? counts[i] : 0;
    s[threadIdx.x] = v;
    __syncthreads();
    for (int off = 1; off < 1024; off <<= 1) {
        int t = (threadIdx.x >= off) ? s[threadIdx.x - off] : 0;
        __syncthreads();
        s[threadIdx.x] += t;
        __syncthreads();
    }
    if (i < N) rowtmp[i] = s[threadIdx.x];
    if (threadIdx.x == 1023) bsum[blockIdx.x] = s[1023];
}

// Fused: block-sum scan (recomputed per block) + row_start/cursor + compaction.
__global__ __launch_bounds__(256) void k_scanC(const int* __restrict__ rowtmp,
                                               const int* __restrict__ counts,
                                               const int* __restrict__ bsum, int nb,
                                               int* __restrict__ row_start,
                                               int* __restrict__ cursor,
                                               const int* __restrict__ flag1,
                                               const int* __restrict__ flag2,
                                               int* __restrict__ list1,
                                               int* __restrict__ list2,
                                               int* __restrict__ cnt1,
                                               int* __restrict__ cnt2, int N) {
    __shared__ int sex[128];
    int tid = threadIdx.x;
    if (tid < 64) {
        int l = tid;
        int a = (2 * l < nb) ? bsum[2 * l] : 0;
        int b = (2 * l + 1 < nb) ? bsum[2 * l + 1] : 0;
        int s = a + b;
        for (int off = 1; off < 64; off <<= 1) {
            int t = __shfl_up(s, off);
            if (l >= off) s += t;
        }
        int excl = s - (a + b);
        sex[2 * l] = excl;
        sex[2 * l + 1] = excl + a;
    }
    __syncthreads();

    int i = blockIdx.x * 256 + tid;
    int lane = tid & 63;
    if (i < N) {
        int st = rowtmp[i] - counts[i] + sex[i >> 10];
        row_start[i] = st;
        cursor[i] = st;
    }

    unsigned long long lt = (lane == 63) ? ~0ull >> 1 : (1ull << lane) - 1;
    bool a = (i < N) && flag1[i];
    unsigned long long m = __ballot(a);
    int base = 0;
    if (lane == 0 && m) base = atomicAdd(cnt1, __popcll(m));
    base = __shfl(base, 0);
    if (a) list1[base + __popcll(m & lt)] = i;

    bool b = (i < N) && flag2[i];
    m = __ballot(b);
    base = 0;
    if (lane == 0 && m) base = atomicAdd(cnt2, __popcll(m));
    base = __shfl(base, 0);
    if (b) list2[base + __popcll(m & lt)] = i;
}

__global__ void k_scatter(const int* __restrict__ dst, int* __restrict__ cursor,
                          int* __restrict__ csr_edge, int E) {
    int e = blockIdx.x * 256 + threadIdx.x;
    if (e < E) {
        int p = atomicAdd(&cursor[dst[e]], 1);
        csr_edge[p] = e;
    }
}

// ---------------------------------------------------------------------------
// R7-EXACT split-bf16 MFMA GEMM (the 387-us config; do not touch):
// grid dim3(4 colchunks, nRowBlk), block 64x64, launch_bounds(256,4),
// B staged to LDS w/ XOR swizzle, fragments via 2x ds_read_b64 + pack,
// A fp32 float4-pair load + in-register hi/lo split (needs the 64-VGPR
// regime -- bounds 5 serializes the A loads and triples FETCH, see R12).
// feat bf16 (c<2) + fused el/er; res fp32 masked by resflag (c>=2).
// ---------------------------------------------------------------------------
__global__ __launch_bounds__(256, 4) void k_gemm_fused(const float* __restrict__ A,
                                                       const unsigned short* __restrict__ Bhi,
                                                       const unsigned short* __restrict__ Blo,
                                                       unsigned short* __restrict__ featb,
                                                       float* __restrict__ res,
                                                       const float* __restrict__ al,
                                                       const float* __restrict__ ar,
                                                       float* __restrict__ el,
                                                       float* __restrict__ er,
                                                       const int* __restrict__ rowlist,
                                                       const int* __restrict__ rowcnt,
                                                       const int* __restrict__ resflag,
                                                       int N) {
    int limit = rowcnt ? *rowcnt : N;
    int c = blockIdx.x;                 // col chunk 0..3
    int m0 = blockIdx.y * 64;
    if (m0 >= limit) return;

    __shared__ unsigned short Bh[8192];
    __shared__ unsigned short Bl[8192];
    int tid = threadIdx.x;
    int lane = tid & 63, w = tid >> 6;
    int wm = (w & 1) * 32, wn = (w >> 1) * 32;
    int lr = lane & 15, g = lane >> 4;

    // stage B chunk (rows c*64..c*64+63), swizzled: byte ^= (row&7)<<4
#pragma unroll
    for (int i = 0; i < 4; ++i) {
        int f = tid + i * 256;
        int row = f >> 4, g16 = f & 15;
        int off = (row * 256 + ((g16 * 16) ^ ((row & 7) << 4))) >> 1;
        *(u16x8*)&Bh[off] = *(const u16x8*)(Bhi + (size_t)(c * 64 + row) * DIM + g16 * 8);
        *(u16x8*)&Bl[off] = *(const u16x8*)(Blo + (size_t)(c * 64 + row) * DIM + g16 * 8);
    }

    // A fragments direct from global -> hi/lo bf16 in registers
    s16x8 afh[2][4], afl[2][4];
#pragma unroll
    for (int fm = 0; fm < 2; ++fm) {
        int idx = m0 + wm + fm * 16 + lr;
        bool valid = idx < limit;
        int grow = 0;
        if (valid) grow = rowlist ? rowlist[idx] : idx;
        const float* ap = A + (size_t)grow * DIM;
#pragma unroll
        for (int ks = 0; ks < 4; ++ks) {
            float4 p = make_float4(0.f, 0.f, 0.f, 0.f);
            float4 q = make_float4(0.f, 0.f, 0.f, 0.f);
            if (valid) {
                p = *(const float4*)(ap + ks * 32 + g * 4);
                q = *(const float4*)(ap + ks * 32 + 16 + g * 4);
            }
            float vv[8] = {p.x, p.y, p.z, p.w, q.x, q.y, q.z, q.w};
            s16x8 hv, lv;
#pragma unroll
            for (int j = 0; j < 8; ++j) {
                unsigned short hh = f2bf_rn(vv[j]);
                hv[j] = (short)hh;
                lv[j] = (short)f2bf_rn(vv[j] - bf2f(hh));
            }
            afh[fm][ks] = hv;
            afl[fm][ks] = lv;
        }
    }
    __syncthreads();

    f32x4 acc[2][2];
#pragma unroll
    for (int fm = 0; fm < 2; ++fm)
#pragma unroll
        for (int fn = 0; fn < 2; ++fn) acc[fm][fn] = (f32x4){0.f, 0.f, 0.f, 0.f};

#pragma unroll
    for (int ks = 0; ks < 4; ++ks) {
        s16x8 bfh[2], bfl[2];
#pragma unroll
        for (int fn = 0; fn < 2; ++fn) {
            int row = wn + fn * 16 + lr;
            int sw = (row & 7) << 4;
            int o1 = (row * 256 + ((ks * 64 + g * 8) ^ sw)) >> 1;
            int o2 = (row * 256 + ((ks * 64 + 32 + g * 8) ^ sw)) >> 1;
            s16x4 p = *(const s16x4*)&Bh[o1];
            s16x4 q = *(const s16x4*)&Bh[o2];
            bfh[fn] = (s16x8){p[0], p[1], p[2], p[3], q[0], q[1], q[2], q[3]};
            p = *(const s16x4*)&Bl[o1];
            q = *(const s16x4*)&Bl[o2];
            bfl[fn] = (s16x8){p[0], p[1], p[2], p[3], q[0], q[1], q[2], q[3]};
        }
#pragma unroll
        for (int fm = 0; fm < 2; ++fm)
#pragma unroll
            for (int fn = 0; fn < 2; ++fn) {
                acc[fm][fn] = __builtin_amdgcn_mfma_f32_16x16x32_bf16(afh[fm][ks], bfh[fn], acc[fm][fn], 0, 0, 0);
                acc[fm][fn] = __builtin_amdgcn_mfma_f32_16x16x32_bf16(afh[fm][ks], bfl[fn], acc[fm][fn], 0, 0, 0);
                acc[fm][fn] = __builtin_amdgcn_mfma_f32_16x16x32_bf16(afl[fm][ks], bfh[fn], acc[fm][fn], 0, 0, 0);
            }
    }

    // ---- C write: feat (bf16) for c<2, masked fp32 res for c>=2 ----
#pragma unroll
    for (int fm = 0; fm < 2; ++fm)
#pragma unroll
        for (int fn = 0; fn < 2; ++fn) {
            int idx0 = m0 + wm + fm * 16 + g * 4;
            int dc = ((c * 64) & 127) + wn + fn * 16 + lr;
#pragma unroll
            for (int r = 0; r < 4; ++r) {
                int idx = idx0 + r;
                if (idx < limit) {
                    int gr = rowlist ? rowlist[idx] : idx;
                    if (c < 2) {
                        featb[(size_t)gr * DIM + dc] = f2bf_rn(acc[fm][fn][r]);
                    } else if (!resflag || resflag[gr]) {
                        res[(size_t)gr * DIM + dc] = acc[fm][fn][r];
                    }
                }
            }
        }

    // ---- fused el/er epilogue from fp32 acc: c<2, head = 2c + wn/32 ----
    if (c < 2) {
        int h = c * 2 + (wn >> 5);
        float a0 = al[h * HID + lr], a1 = al[h * HID + 16 + lr];
        float b0 = ar[h * HID + lr], b1 = ar[h * HID + 16 + lr];
#pragma unroll
        for (int fm = 0; fm < 2; ++fm)
#pragma unroll
            for (int r = 0; r < 4; ++r) {
                float ev = acc[fm][0][r] * a0 + acc[fm][1][r] * a1;
                float rv = acc[fm][0][r] * b0 + acc[fm][1][r] * b1;
#pragma unroll
                for (int off = 1; off < 16; off <<= 1) {
                    ev += __shfl_xor(ev, off);
                    rv += __shfl_xor(rv, off);
                }
                if (lr == 0) {
                    int idx = m0 + wm + fm * 16 + g * 4 + r;
                    if (idx < limit) {
                        int node = rowlist ? rowlist[idx] : idx;
                        el[node * 4 + h] = ev;
                        er[node * 4 + h] = rv;
                    }
                }
            }
    }
}

// ---------------------------------------------------------------------------
// Aggregation over a dst-node list: one wave per listed dst node. feat bf16.
// ---------------------------------------------------------------------------
template <int RELU>
__global__ __launch_bounds__(256) void k_agg(const unsigned short* __restrict__ featb,
                                             const float* __restrict__ el,
                                             const float* __restrict__ er,
                                             const float* __restrict__ eeB,
                                             const int* __restrict__ srcArr,
                                             const int* __restrict__ etArr,
                                             const int* __restrict__ csr_edge,
                                             const int* __restrict__ row_start,
                                             const int* __restrict__ counts,
                                             const int* __restrict__ dlist,
                                             const int* __restrict__ dcnt,
                                             float* __restrict__ out) {
    int wv = threadIdx.x >> 6;
    int lane = threadIdx.x & 63;
    int idx = blockIdx.x * 4 + wv;
    if (idx >= *dcnt) return;
    int node = dlist[idx];

    int beg = row_start[node];
    int deg = counts[node];
    int eh = lane & 3;
    float er_v = er[node * 4 + eh];

    float m = -INFINITY;
    for (int base = 0; base < deg; base += 16) {
        int ei = base + (lane >> 2);
        float lg = -INFINITY;
        if (ei < deg) {
            int e = csr_edge[beg + ei];
            float x = el[srcArr[e] * 4 + eh] + er_v + eeB[etArr[e] * 4 + eh];
            lg = (x > 0.f) ? x : 0.2f * x;
        }
        m = fmaxf(m, lg);
    }
    for (int off = 4; off < 64; off <<= 1) m = fmaxf(m, __shfl_xor(m, off));

    float denom = 0.f, acc0 = 0.f, acc1 = 0.f;
    int h1 = lane >> 5;
    for (int base = 0; base < deg; base += 16) {
        int ei = base + (lane >> 2);
        float wgt = 0.f;
        int s = 0;
        if (ei < deg) {
            int e = csr_edge[beg + ei];
            s = srcArr[e];
            float x = el[s * 4 + eh] + er_v + eeB[etArr[e] * 4 + eh];
            x = (x > 0.f) ? x : 0.2f * x;
            wgt = expf(x - m);
            denom += wgt;
        }
        int cnt = min(16, deg - base);
        for (int j = 0; j < cnt; ++j) {
            int sj = __shfl(s, j * 4);
            float w1 = __shfl(wgt, j * 4 + h1);
            float w2 = __shfl(wgt, j * 4 + 2 + h1);
            acc0 += w1 * bf2f(featb[(size_t)sj * DIM + lane]);
            acc1 += w2 * bf2f(featb[(size_t)sj * DIM + 64 + lane]);
        }
    }
    for (int off = 4; off < 64; off <<= 1) denom += __shfl_xor(denom, off);
    float d1 = __shfl(denom, h1);
    float d2 = __shfl(denom, 2 + h1);

    float r0 = out[(size_t)node * DIM + lane] + acc0 / (d1 + 1e-16f);
    float r1 = out[(size_t)node * DIM + 64 + lane] + acc1 / (d2 + 1e-16f);
    if (RELU) { r0 = fmaxf(r0, 0.f); r1 = fmaxf(r1, 0.f); }
    out[(size_t)node * DIM + lane] = r0;
    out[(size_t)node * DIM + 64 + lane] = r1;
}

// ---------------------------------------------------------------------------
// Head MLP
// ---------------------------------------------------------------------------
__global__ __launch_bounds__(256) void k_head(const float* __restrict__ x1,
                                              const int* __restrict__ n_id,
                                              const float* __restrict__ pW1,
                                              const float* __restrict__ pb1,
                                              const float* __restrict__ pW2,
                                              const float* __restrict__ pb2,
                                              float* __restrict__ dout, int B) {
    int o = blockIdx.x * 4 + (threadIdx.x >> 6);
    int lane = threadIdx.x & 63;
    int total = B + B * NEGS;
    if (o >= total) return;
    int a, c;
    if (o < B) { a = n_id[o]; c = n_id[B + o]; }
    else { int j = o - B; a = n_id[j / NEGS]; c = n_id[2 * B + j]; }

    int j = lane & 31;
    int half = lane >> 5;
    int row = half ? c : a;
    const float* z = x1 + (size_t)row * DIM;
    const float* w = pW1 + (half ? 128 * 32 : 0);
    float t = 0.f;
#pragma unroll 8
    for (int k = 0; k < 128; ++k) t += z[k] * w[k * 32 + j];
    t += __shfl_xor(t, 32);
    t += pb1[j];
    t = (t > 0.f) ? t : 0.2f * t;
    float r = t * pW2[j];
    for (int off = 1; off < 32; off <<= 1) r += __shfl_xor(r, off);
    if (lane == 0) dout[o] = r + pb2[0];
}

// ---------------------------------------------------------------------------
extern "C" void kernel_launch(void* const* d_in, const int* in_sizes, int n_in,
                              void* d_out, int out_size, void* d_ws, size_t ws_size,
                              hipStream_t stream) {
    const int* edge_index = (const int*)d_in[0];
    const int* etype      = (const int*)d_in[1];
    const int* n_id       = (const int*)d_in[2];
    const float* id_emb   = (const float*)d_in[4];
    const float* W0    = (const float*)d_in[5];
    const float* Wres0 = (const float*)d_in[6];
    const float* al0   = (const float*)d_in[7];
    const float* ar0   = (const float*)d_in[8];
    const float* ae0   = (const float*)d_in[9];
    const float* eemb0 = (const float*)d_in[10];
    const float* We0   = (const float*)d_in[11];
    const float* W1    = (const float*)d_in[12];
    const float* Wres1 = (const float*)d_in[13];
    const float* al1   = (const float*)d_in[14];
    const float* ar1   = (const float*)d_in[15];
    const float* ae1   = (const float*)d_in[16];
    const float* eemb1 = (const float*)d_in[17];
    const float* We1   = (const float*)d_in[18];
    const float* pW1   = (const float*)d_in[19];
    const float* pb1   = (const float*)d_in[20];
    const float* pW2   = (const float*)d_in[21];
    const float* pb2   = (const float*)d_in[22];

    int E = in_sizes[1];
    int N = in_sizes[4] / DIM;
    int M = in_sizes[2];
    int B = M / (2 + NEGS);
    const int* srcArr = edge_index;
    const int* dstArr = edge_index + E;

    size_t N128 = (size_t)N * DIM;
    unsigned short* featb = (unsigned short*)d_ws;     // N128 u16
    float* x0   = (float*)(featb + N128);              // N128 f32
    float* x1   = x0 + N128;                           // N128 f32
    float* el   = x1 + N128;
    float* er   = el + (size_t)N * 4;
    float* eeB  = er + (size_t)N * 4;                  // 32 floats (both layers)
    int* counts    = (int*)(eeB + 32);
    int* flag1     = counts + N;
    int* flag2     = flag1 + N;
    int* cnt1      = flag2 + N;
    int* cnt2      = cnt1 + 1;
    int* rowtmp    = cnt2 + 1;
    int* row_start = rowtmp + N;
    int* cursor    = row_start + N;
    int* csr_edge  = cursor + N;
    int* list1     = csr_edge + E;
    int* list2     = list1 + N;
    int* bsum      = list2 + M;
    unsigned short* bt = (unsigned short*)(bsum + 256);

    // ---- setup: zero(3N+2) + wcvt (R7 layout) + both ee tables ----
    k_setup<<<256, 256, 0, stream>>>(W0, Wres0, W1, Wres1,
                                     eemb0, We0, ae0, eemb1, We1, ae1,
                                     bt, eeB, counts, 3 * N + 2);

    // ---- flags, CSR ----
    k_flag2<<<(M + 255) / 256, 256, 0, stream>>>(n_id, flag2, flag1, M);
    k_histflag<<<(E + 255) / 256, 256, 0, stream>>>(srcArr, dstArr, flag2, counts, flag1, E);
    int nb = (N + 1023) / 1024;
    k_scanA<<<nb, 1024, 0, stream>>>(counts, rowtmp, bsum, N);
    k_scanC<<<(N + 255) / 256, 256, 0, stream>>>(rowtmp, counts, bsum, nb, row_start, cursor,
                                                 flag1, flag2, list1, list2, cnt1, cnt2, N);
    k_scatter<<<(E + 255) / 256, 256, 0, stream>>>(dstArr, cursor, csr_edge, E);

    dim3 ggrid(4, (N + 63) / 64);
    int aggGridFull = (N + 3) / 4;
    int aggGridS2 = (M + 3) / 4;

    // ---- layer 0: feat bf16 full N; res (x0) only flag1 rows ----
    k_gemm_fused<<<ggrid, 256, 0, stream>>>(id_emb, bt, bt + 32768, featb, x0,
                                            al0, ar0, el, er, nullptr, nullptr, flag1, N);
    k_agg<1><<<aggGridFull, 256, 0, stream>>>(featb, el, er, eeB, srcArr, etype, csr_edge,
                                              row_start, counts, list1, cnt1, x0);

    // ---- layer 1: rows = list1; res (x1) only flag2 rows ----
    k_gemm_fused<<<ggrid, 256, 0, stream>>>(x0, bt + 65536, bt + 98304, featb, x1,
                                            al1, ar1, el, er, list1, cnt1, flag2, N);
    k_agg<0><<<aggGridS2, 256, 0, stream>>>(featb, el, er, eeB + 16, srcArr, etype, csr_edge,
                                            row_start, counts, list2, cnt2, x1);

    // ---- head ----
    int total = B * (1 + NEGS);
    k_head<<<(total + 3) / 4, 256, 0, stream>>>(x1, n_id, pW1, pb1, pW2, pb2,
                                                (float*)d_out, B);
}

// Round 14
// 336.874 us; speedup vs baseline: 1.4384x; 1.0971x over previous
//
#include <hip/hip_runtime.h>
#include <hip/hip_bf16.h>
#include <math.h>

#define HEADS 4
#define HID 32
#define DIM 128
#define NEGS 5

typedef short s16x8 __attribute__((ext_vector_type(8)));
typedef short s16x4 __attribute__((ext_vector_type(4)));
typedef unsigned short u16x8 __attribute__((ext_vector_type(8)));
typedef float f32x4 __attribute__((ext_vector_type(4)));

__device__ __forceinline__ unsigned short f2bf_rn(float x) {
    unsigned int u = __float_as_uint(x);
    unsigned int r = (u + 0x7FFFu + ((u >> 16) & 1u)) >> 16;
    return (unsigned short)r;
}
__device__ __forceinline__ float bf2f(unsigned short b) {
    return __uint_as_float(((unsigned int)b) << 16);
}

// ---------------------------------------------------------------------------
// Setup: zero counters/flags + weight preconvert (R7 layout: bt[layer][hi/lo]
// [n][k]) + both ee tables. Grid MUST be 256 x 256.
// ---------------------------------------------------------------------------
__global__ void k_setup(const float* __restrict__ W0, const float* __restrict__ Wres0,
                        const float* __restrict__ W1, const float* __restrict__ Wres1,
                        const float* __restrict__ eemb0, const float* __restrict__ We0,
                        const float* __restrict__ ae0,
                        const float* __restrict__ eemb1, const float* __restrict__ We1,
                        const float* __restrict__ ae1,
                        unsigned short* __restrict__ bt, float* __restrict__ eeB,
                        int* __restrict__ zbase, int zn) {
    int idx = blockIdx.x * 256 + threadIdx.x;

    for (int i = idx; i < zn; i += 65536) zbase[i] = 0;

    {
        int layer = idx >> 15;
        int r = idx & 32767;
        int k = r >> 8;
        int n = r & 255;
        const float* src = layer ? ((n < 128) ? W1 : Wres1) : ((n < 128) ? W0 : Wres0);
        float x = src[k * 128 + (n & 127)];
        unsigned short h = f2bf_rn(x);
        unsigned short l = f2bf_rn(x - bf2f(h));
        unsigned short* base = bt + (size_t)layer * 2 * 32768;
        base[n * 128 + k] = h;
        base[32768 + n * 128 + k] = l;
    }

    if (idx < 32) {
        int layer = idx >> 4, t = idx & 15;
        const float* eemb = layer ? eemb1 : eemb0;
        const float* We   = layer ? We1 : We0;
        const float* ae   = layer ? ae1 : ae0;
        int et = t >> 2, h = t & 3;
        float s = 0.f;
        for (int d = 0; d < 32; ++d) {
            float ef = 0.f;
            for (int k = 0; k < 32; ++k) ef += eemb[et * 32 + k] * We[k * DIM + h * 32 + d];
            s += ef * ae[h * 32 + d];
        }
        eeB[layer * 16 + t] = s;
    }
}

// ---------------------------------------------------------------------------
// Flags + CSR build
// ---------------------------------------------------------------------------
__global__ void k_flag2(const int* __restrict__ n_id, int* __restrict__ flag2,
                        int* __restrict__ flag1, int M) {
    int i = blockIdx.x * 256 + threadIdx.x;
    if (i < M) { int n = n_id[i]; flag2[n] = 1; flag1[n] = 1; }
}

__global__ void k_histflag(const int* __restrict__ src, const int* __restrict__ dst,
                           const int* __restrict__ flag2,
                           int* __restrict__ counts, int* __restrict__ flag1, int E) {
    int e = blockIdx.x * 256 + threadIdx.x;
    if (e < E) {
        int d = dst[e];
        atomicAdd(&counts[d], 1);
        if (flag2[d]) flag1[src[e]] = 1;
    }
}

__global__ __launch_bounds__(1024) void k_scanA(const int* __restrict__ counts,
                                                int* __restrict__ rowtmp,
                                                int* __restrict__ bsum, int N) {
    __shared__ int s[1024];
    int i = blockIdx.x * 1024 + threadIdx.x;
    int v = (i < N) ? counts[i] : 0;
    s[threadIdx.x] = v;
    __syncthreads();
    for (int off = 1; off < 1024; off <<= 1) {
        int t = (threadIdx.x >= off) ? s[threadIdx.x - off] : 0;
        __syncthreads();
        s[threadIdx.x] += t;
        __syncthreads();
    }
    if (i < N) rowtmp[i] = s[threadIdx.x];
    if (threadIdx.x == 1023) bsum[blockIdx.x] = s[1023];
}

// Fused: block-sum scan (recomputed per block) + row_start/cursor + compaction.
__global__ __launch_bounds__(256) void k_scanC(const int* __restrict__ rowtmp,
                                               const int* __restrict__ counts,
                                               const int* __restrict__ bsum, int nb,
                                               int* __restrict__ row_start,
                                               int* __restrict__ cursor,
                                               const int* __restrict__ flag1,
                                               const int* __restrict__ flag2,
                                               int* __restrict__ list1,
                                               int* __restrict__ list2,
                                               int* __restrict__ cnt1,
                                               int* __restrict__ cnt2, int N) {
    __shared__ int sex[128];
    int tid = threadIdx.x;
    if (tid < 64) {
        int l = tid;
        int a = (2 * l < nb) ? bsum[2 * l] : 0;
        int b = (2 * l + 1 < nb) ? bsum[2 * l + 1] : 0;
        int s = a + b;
        for (int off = 1; off < 64; off <<= 1) {
            int t = __shfl_up(s, off);
            if (l >= off) s += t;
        }
        int excl = s - (a + b);
        sex[2 * l] = excl;
        sex[2 * l + 1] = excl + a;
    }
    __syncthreads();

    int i = blockIdx.x * 256 + tid;
    int lane = tid & 63;
    if (i < N) {
        int st = rowtmp[i] - counts[i] + sex[i >> 10];
        row_start[i] = st;
        cursor[i] = st;
    }

    unsigned long long lt = (lane == 63) ? ~0ull >> 1 : (1ull << lane) - 1;
    bool a = (i < N) && flag1[i];
    unsigned long long m = __ballot(a);
    int base = 0;
    if (lane == 0 && m) base = atomicAdd(cnt1, __popcll(m));
    base = __shfl(base, 0);
    if (a) list1[base + __popcll(m & lt)] = i;

    bool b = (i < N) && flag2[i];
    m = __ballot(b);
    base = 0;
    if (lane == 0 && m) base = atomicAdd(cnt2, __popcll(m));
    base = __shfl(base, 0);
    if (b) list2[base + __popcll(m & lt)] = i;
}

__global__ void k_scatter(const int* __restrict__ dst, int* __restrict__ cursor,
                          int* __restrict__ csr_edge, int E) {
    int e = blockIdx.x * 256 + threadIdx.x;
    if (e < E) {
        int p = atomicAdd(&cursor[dst[e]], 1);
        csr_edge[p] = e;
    }
}

// ---------------------------------------------------------------------------
// Split-bf16 MFMA GEMM, R7 block structure with 4x1 wave decomposition:
// grid dim3(4 colchunks, nRowBlk), block = 64 rows x 64 cols, wave w owns
// rows w*16..w*16+15 x ALL 64 cols. Each A row loaded+converted by exactly
// ONE wave (in-block A redundancy 2x -> 1x; convert VALU halves); B shared
// through LDS (that's what it's for). Same LDS staging/swizzle, same barrier,
// same write coverage, launch_bounds(256,4) (64-VGPR regime; see R12).
// Per-output MFMA sequence identical to R7 -> bit-identical numerics.
// feat bf16 (c<2) + fused el/er (both heads of the chunk); res masked (c>=2).
// ---------------------------------------------------------------------------
__global__ __launch_bounds__(256, 4) void k_gemm_fused(const float* __restrict__ A,
                                                       const unsigned short* __restrict__ Bhi,
                                                       const unsigned short* __restrict__ Blo,
                                                       unsigned short* __restrict__ featb,
                                                       float* __restrict__ res,
                                                       const float* __restrict__ al,
                                                       const float* __restrict__ ar,
                                                       float* __restrict__ el,
                                                       float* __restrict__ er,
                                                       const int* __restrict__ rowlist,
                                                       const int* __restrict__ rowcnt,
                                                       const int* __restrict__ resflag,
                                                       int N) {
    int limit = rowcnt ? *rowcnt : N;
    int c = blockIdx.x;                 // col chunk 0..3
    int m0 = blockIdx.y * 64;
    if (m0 >= limit) return;

    __shared__ unsigned short Bh[8192];
    __shared__ unsigned short Bl[8192];
    int tid = threadIdx.x;
    int lane = tid & 63, w = tid >> 6;
    int lr = lane & 15, g = lane >> 4;

    // stage B chunk (rows c*64..c*64+63), swizzled: byte ^= (row&7)<<4
#pragma unroll
    for (int i = 0; i < 4; ++i) {
        int f = tid + i * 256;
        int row = f >> 4, g16 = f & 15;
        int off = (row * 256 + ((g16 * 16) ^ ((row & 7) << 4))) >> 1;
        *(u16x8*)&Bh[off] = *(const u16x8*)(Bhi + (size_t)(c * 64 + row) * DIM + g16 * 8);
        *(u16x8*)&Bl[off] = *(const u16x8*)(Blo + (size_t)(c * 64 + row) * DIM + g16 * 8);
    }

    // A fragments: this wave's 16 rows, loaded ONCE -> hi/lo bf16 in registers
    s16x8 afh[4], afl[4];
    {
        int aidx = m0 + w * 16 + lr;
        bool valid = aidx < limit;
        int grow = 0;
        if (valid) grow = rowlist ? rowlist[aidx] : aidx;
        const float* ap = A + (size_t)grow * DIM;
#pragma unroll
        for (int ks = 0; ks < 4; ++ks) {
            float4 p = make_float4(0.f, 0.f, 0.f, 0.f);
            float4 q = make_float4(0.f, 0.f, 0.f, 0.f);
            if (valid) {
                p = *(const float4*)(ap + ks * 32 + g * 4);
                q = *(const float4*)(ap + ks * 32 + 16 + g * 4);
            }
            float vv[8] = {p.x, p.y, p.z, p.w, q.x, q.y, q.z, q.w};
            s16x8 hv, lv;
#pragma unroll
            for (int j = 0; j < 8; ++j) {
                unsigned short hh = f2bf_rn(vv[j]);
                hv[j] = (short)hh;
                lv[j] = (short)f2bf_rn(vv[j] - bf2f(hh));
            }
            afh[ks] = hv;
            afl[ks] = lv;
        }
    }
    __syncthreads();

    f32x4 acc[4];
#pragma unroll
    for (int fn = 0; fn < 4; ++fn) acc[fn] = (f32x4){0.f, 0.f, 0.f, 0.f};

#pragma unroll
    for (int ks = 0; ks < 4; ++ks) {
        s16x8 bfh[4], bfl[4];
#pragma unroll
        for (int fn = 0; fn < 4; ++fn) {
            int row = fn * 16 + lr;
            int sw = (row & 7) << 4;
            int o1 = (row * 256 + ((ks * 64 + g * 8) ^ sw)) >> 1;
            int o2 = (row * 256 + ((ks * 64 + 32 + g * 8) ^ sw)) >> 1;
            s16x4 p = *(const s16x4*)&Bh[o1];
            s16x4 q = *(const s16x4*)&Bh[o2];
            bfh[fn] = (s16x8){p[0], p[1], p[2], p[3], q[0], q[1], q[2], q[3]};
            p = *(const s16x4*)&Bl[o1];
            q = *(const s16x4*)&Bl[o2];
            bfl[fn] = (s16x8){p[0], p[1], p[2], p[3], q[0], q[1], q[2], q[3]};
        }
#pragma unroll
        for (int fn = 0; fn < 4; ++fn) {
            acc[fn] = __builtin_amdgcn_mfma_f32_16x16x32_bf16(afh[ks], bfh[fn], acc[fn], 0, 0, 0);
            acc[fn] = __builtin_amdgcn_mfma_f32_16x16x32_bf16(afh[ks], bfl[fn], acc[fn], 0, 0, 0);
            acc[fn] = __builtin_amdgcn_mfma_f32_16x16x32_bf16(afl[ks], bfh[fn], acc[fn], 0, 0, 0);
        }
    }

    // ---- C write: feat (bf16) for c<2, masked fp32 res for c>=2 ----
    int idx0 = m0 + w * 16 + g * 4;
#pragma unroll
    for (int fn = 0; fn < 4; ++fn) {
        int dc = ((c * 64) & 127) + fn * 16 + lr;
#pragma unroll
        for (int r = 0; r < 4; ++r) {
            int idx = idx0 + r;
            if (idx < limit) {
                int gr = rowlist ? rowlist[idx] : idx;
                if (c < 2) {
                    featb[(size_t)gr * DIM + dc] = f2bf_rn(acc[fn][r]);
                } else if (!resflag || resflag[gr]) {
                    res[(size_t)gr * DIM + dc] = acc[fn][r];
                }
            }
        }
    }

    // ---- fused el/er epilogue: c<2, this wave covers BOTH heads 2c, 2c+1 ----
    if (c < 2) {
        int h0 = c * 2, h1 = c * 2 + 1;
        float a00 = al[h0 * HID + lr], a01 = al[h0 * HID + 16 + lr];
        float a10 = al[h1 * HID + lr], a11 = al[h1 * HID + 16 + lr];
        float b00 = ar[h0 * HID + lr], b01 = ar[h0 * HID + 16 + lr];
        float b10 = ar[h1 * HID + lr], b11 = ar[h1 * HID + 16 + lr];
#pragma unroll
        for (int r = 0; r < 4; ++r) {
            float ev0 = acc[0][r] * a00 + acc[1][r] * a01;
            float rv0 = acc[0][r] * b00 + acc[1][r] * b01;
            float ev1 = acc[2][r] * a10 + acc[3][r] * a11;
            float rv1 = acc[2][r] * b10 + acc[3][r] * b11;
#pragma unroll
            for (int off = 1; off < 16; off <<= 1) {
                ev0 += __shfl_xor(ev0, off);
                rv0 += __shfl_xor(rv0, off);
                ev1 += __shfl_xor(ev1, off);
                rv1 += __shfl_xor(rv1, off);
            }
            if (lr == 0) {
                int idx = idx0 + r;
                if (idx < limit) {
                    int node = rowlist ? rowlist[idx] : idx;
                    el[node * 4 + h0] = ev0;
                    er[node * 4 + h0] = rv0;
                    el[node * 4 + h1] = ev1;
                    er[node * 4 + h1] = rv1;
                }
            }
        }
    }
}

// ---------------------------------------------------------------------------
// Aggregation: one wave per listed dst node. feat bf16, gathered as ONE
// u32/lane (channels 2l,2l+1 -> 256 B/wave per load); float2 output stores.
// Per-channel math identical to R13 (same edge order, same weights).
// ---------------------------------------------------------------------------
template <int RELU>
__global__ __launch_bounds__(256) void k_agg(const unsigned short* __restrict__ featb,
                                             const float* __restrict__ el,
                                             const float* __restrict__ er,
                                             const float* __restrict__ eeB,
                                             const int* __restrict__ srcArr,
                                             const int* __restrict__ etArr,
                                             const int* __restrict__ csr_edge,
                                             const int* __restrict__ row_start,
                                             const int* __restrict__ counts,
                                             const int* __restrict__ dlist,
                                             const int* __restrict__ dcnt,
                                             float* __restrict__ out) {
    int wv = threadIdx.x >> 6;
    int lane = threadIdx.x & 63;
    int idx = blockIdx.x * 4 + wv;
    if (idx >= *dcnt) return;
    int node = dlist[idx];

    int beg = row_start[node];
    int deg = counts[node];
    int eh = lane & 3;                 // head this lane evaluates logits for
    int hc = lane >> 4;                // head of this lane's channel pair
    float er_v = er[node * 4 + eh];

    float m = -INFINITY;
    for (int base = 0; base < deg; base += 16) {
        int ei = base + (lane >> 2);
        float lg = -INFINITY;
        if (ei < deg) {
            int e = csr_edge[beg + ei];
            float x = el[srcArr[e] * 4 + eh] + er_v + eeB[etArr[e] * 4 + eh];
            lg = (x > 0.f) ? x : 0.2f * x;
        }
        m = fmaxf(m, lg);
    }
    for (int off = 4; off < 64; off <<= 1) m = fmaxf(m, __shfl_xor(m, off));

    float denom = 0.f, acc0 = 0.f, acc1 = 0.f;
    for (int base = 0; base < deg; base += 16) {
        int ei = base + (lane >> 2);
        float wgt = 0.f;
        int s = 0;
        if (ei < deg) {
            int e = csr_edge[beg + ei];
            s = srcArr[e];
            float x = el[s * 4 + eh] + er_v + eeB[etArr[e] * 4 + eh];
            x = (x > 0.f) ? x : 0.2f * x;
            wgt = expf(x - m);
            denom += wgt;
        }
        int cnt = min(16, deg - base);
        for (int j = 0; j < cnt; ++j) {
            int sj = __shfl(s, j * 4);
            float ww = __shfl(wgt, j * 4 + hc);
            unsigned int pv = *(const unsigned int*)(featb + (size_t)sj * DIM + 2 * lane);
            acc0 += ww * bf2f((unsigned short)(pv & 0xFFFFu));
            acc1 += ww * bf2f((unsigned short)(pv >> 16));
        }
    }
    for (int off = 4; off < 64; off <<= 1) denom += __shfl_xor(denom, off);
    float d = __shfl(denom, hc);       // lane hc holds denom of head hc

    float2 prev = *(const float2*)(out + (size_t)node * DIM + 2 * lane);
    float r0 = prev.x + acc0 / (d + 1e-16f);
    float r1 = prev.y + acc1 / (d + 1e-16f);
    if (RELU) { r0 = fmaxf(r0, 0.f); r1 = fmaxf(r1, 0.f); }
    *(float2*)(out + (size_t)node * DIM + 2 * lane) = make_float2(r0, r1);
}

// ---------------------------------------------------------------------------
// Head MLP
// ---------------------------------------------------------------------------
__global__ __launch_bounds__(256) void k_head(const float* __restrict__ x1,
                                              const int* __restrict__ n_id,
                                              const float* __restrict__ pW1,
                                              const float* __restrict__ pb1,
                                              const float* __restrict__ pW2,
                                              const float* __restrict__ pb2,
                                              float* __restrict__ dout, int B) {
    int o = blockIdx.x * 4 + (threadIdx.x >> 6);
    int lane = threadIdx.x & 63;
    int total = B + B * NEGS;
    if (o >= total) return;
    int a, c;
    if (o < B) { a = n_id[o]; c = n_id[B + o]; }
    else { int j = o - B; a = n_id[j / NEGS]; c = n_id[2 * B + j]; }

    int j = lane & 31;
    int half = lane >> 5;
    int row = half ? c : a;
    const float* z = x1 + (size_t)row * DIM;
    const float* w = pW1 + (half ? 128 * 32 : 0);
    float t = 0.f;
#pragma unroll 8
    for (int k = 0; k < 128; ++k) t += z[k] * w[k * 32 + j];
    t += __shfl_xor(t, 32);
    t += pb1[j];
    t = (t > 0.f) ? t : 0.2f * t;
    float r = t * pW2[j];
    for (int off = 1; off < 32; off <<= 1) r += __shfl_xor(r, off);
    if (lane == 0) dout[o] = r + pb2[0];
}

// ---------------------------------------------------------------------------
extern "C" void kernel_launch(void* const* d_in, const int* in_sizes, int n_in,
                              void* d_out, int out_size, void* d_ws, size_t ws_size,
                              hipStream_t stream) {
    const int* edge_index = (const int*)d_in[0];
    const int* etype      = (const int*)d_in[1];
    const int* n_id       = (const int*)d_in[2];
    const float* id_emb   = (const float*)d_in[4];
    const float* W0    = (const float*)d_in[5];
    const float* Wres0 = (const float*)d_in[6];
    const float* al0   = (const float*)d_in[7];
    const float* ar0   = (const float*)d_in[8];
    const float* ae0   = (const float*)d_in[9];
    const float* eemb0 = (const float*)d_in[10];
    const float* We0   = (const float*)d_in[11];
    const float* W1    = (const float*)d_in[12];
    const float* Wres1 = (const float*)d_in[13];
    const float* al1   = (const float*)d_in[14];
    const float* ar1   = (const float*)d_in[15];
    const float* ae1   = (const float*)d_in[16];
    const float* eemb1 = (const float*)d_in[17];
    const float* We1   = (const float*)d_in[18];
    const float* pW1   = (const float*)d_in[19];
    const float* pb1   = (const float*)d_in[20];
    const float* pW2   = (const float*)d_in[21];
    const float* pb2   = (const float*)d_in[22];

    int E = in_sizes[1];
    int N = in_sizes[4] / DIM;
    int M = in_sizes[2];
    int B = M / (2 + NEGS);
    const int* srcArr = edge_index;
    const int* dstArr = edge_index + E;

    size_t N128 = (size_t)N * DIM;
    unsigned short* featb = (unsigned short*)d_ws;     // N128 u16
    float* x0   = (float*)(featb + N128);              // N128 f32
    float* x1   = x0 + N128;                           // N128 f32
    float* el   = x1 + N128;
    float* er   = el + (size_t)N * 4;
    float* eeB  = er + (size_t)N * 4;                  // 32 floats (both layers)
    int* counts    = (int*)(eeB + 32);
    int* flag1     = counts + N;
    int* flag2     = flag1 + N;
    int* cnt1      = flag2 + N;
    int* cnt2      = cnt1 + 1;
    int* rowtmp    = cnt2 + 1;
    int* row_start = rowtmp + N;
    int* cursor    = row_start + N;
    int* csr_edge  = cursor + N;
    int* list1     = csr_edge + E;
    int* list2     = list1 + N;
    int* bsum      = list2 + M;
    unsigned short* bt = (unsigned short*)(bsum + 256);

    // ---- setup: zero(3N+2) + wcvt (R7 layout) + both ee tables ----
    k_setup<<<256, 256, 0, stream>>>(W0, Wres0, W1, Wres1,
                                     eemb0, We0, ae0, eemb1, We1, ae1,
                                     bt, eeB, counts, 3 * N + 2);

    // ---- flags, CSR ----
    k_flag2<<<(M + 255) / 256, 256, 0, stream>>>(n_id, flag2, flag1, M);
    k_histflag<<<(E + 255) / 256, 256, 0, stream>>>(srcArr, dstArr, flag2, counts, flag1, E);
    int nb = (N + 1023) / 1024;
    k_scanA<<<nb, 1024, 0, stream>>>(counts, rowtmp, bsum, N);
    k_scanC<<<(N + 255) / 256, 256, 0, stream>>>(rowtmp, counts, bsum, nb, row_start, cursor,
                                                 flag1, flag2, list1, list2, cnt1, cnt2, N);
    k_scatter<<<(E + 255) / 256, 256, 0, stream>>>(dstArr, cursor, csr_edge, E);

    dim3 ggrid(4, (N + 63) / 64);
    int aggGridFull = (N + 3) / 4;
    int aggGridS2 = (M + 3) / 4;

    // ---- layer 0: feat bf16 full N; res (x0) only flag1 rows ----
    k_gemm_fused<<<ggrid, 256, 0, stream>>>(id_emb, bt, bt + 32768, featb, x0,
                                            al0, ar0, el, er, nullptr, nullptr, flag1, N);
    k_agg<1><<<aggGridFull, 256, 0, stream>>>(featb, el, er, eeB, srcArr, etype, csr_edge,
                                              row_start, counts, list1, cnt1, x0);

    // ---- layer 1: rows = list1; res (x1) only flag2 rows ----
    k_gemm_fused<<<ggrid, 256, 0, stream>>>(x0, bt + 65536, bt + 98304, featb, x1,
                                            al1, ar1, el, er, list1, cnt1, flag2, N);
    k_agg<0><<<aggGridS2, 256, 0, stream>>>(featb, el, er, eeB + 16, srcArr, etype, csr_edge,
                                            row_start, counts, list2, cnt2, x1);

    // ---- head ----
    int total = B * (1 + NEGS);
    k_head<<<(total + 3) / 4, 256, 0, stream>>>(x1, n_id, pW1, pb1, pW2, pb2,
                                                (float*)d_out, B);
}